// Round 6
// baseline (1284.092 us; speedup 1.0000x reference)
//
#include <hip/hip_runtime.h>
#include <math.h>

#define WPB 4          // waves per block
#define BLOCK 256
#define GRID 2048

// ---------------------------------------------------------------------------
// Main kernel: one wave per row, grid-stride over rows.
// Each wave computes ce = logsumexp(row) - row[label], masked by
// keep = !(label in min_classes); accumulates (ce*keep, keep) in doubles.
// Per-block partials written to part[0..nblocks) (ce) and
// part[nblocks..2*nblocks) (keep count). No atomics -> deterministic,
// no dependence on 0xAA-poisoned workspace contents.
// ---------------------------------------------------------------------------
extern "C" __global__ __launch_bounds__(BLOCK) void crl_main(
    const float* __restrict__ score, const int* __restrict__ label,
    const int* __restrict__ minc, int N, int C, int nmin,
    double* __restrict__ part, int nblocks)
{
    __shared__ unsigned char minmap[1024];
    for (int i = threadIdx.x; i < 1024; i += BLOCK) minmap[i] = 0;
    __syncthreads();
    for (int i = threadIdx.x; i < nmin; i += BLOCK) {
        int c = minc[i];
        if (c >= 0 && c < 1024) minmap[c] = 1;
    }
    __syncthreads();

    const int lane = threadIdx.x & 63;
    const int wave = threadIdx.x >> 6;
    const int gw   = blockIdx.x * WPB + wave;
    const int nw   = gridDim.x * WPB;
    const int nf4  = C >> 2;            // 250 for C=1000
    const int rem  = C - (nf4 << 2);    // 0 for C=1000

    double acc_ce = 0.0, acc_k = 0.0;

    for (int r = gw; r < N; r += nw) {
        const float*  rowf = score + (size_t)r * C;
        const float4* row  = reinterpret_cast<const float4*>(rowf);
        const int lbl = label[r];

        // Load entire row into registers (<= 4 float4 per lane) + scalar tail.
        float4 v[4];
        #pragma unroll
        for (int j = 0; j < 4; j++) {
            int f = lane + j * 64;
            if (f < nf4) {
                v[j] = row[f];
            } else {
                v[j].x = -INFINITY; v[j].y = -INFINITY;
                v[j].z = -INFINITY; v[j].w = -INFINITY;
            }
        }
        float t = (lane < rem) ? rowf[(nf4 << 2) + lane] : -INFINITY;

        // Row max (exact, matches reference log_softmax stabilization).
        float m = t;
        #pragma unroll
        for (int j = 0; j < 4; j++)
            m = fmaxf(m, fmaxf(fmaxf(v[j].x, v[j].y), fmaxf(v[j].z, v[j].w)));
        #pragma unroll
        for (int o = 32; o > 0; o >>= 1) m = fmaxf(m, __shfl_xor(m, o));

        // Sum of exp + pick out x[label] in the same register pass.
        float s = 0.f, xl = 0.f;
        #pragma unroll
        for (int j = 0; j < 4; j++) {
            int base = (lane + j * 64) << 2;
            s += __expf(v[j].x - m);
            s += __expf(v[j].y - m);
            s += __expf(v[j].z - m);
            s += __expf(v[j].w - m);
            if (base + 0 == lbl) xl = v[j].x;
            if (base + 1 == lbl) xl = v[j].y;
            if (base + 2 == lbl) xl = v[j].z;
            if (base + 3 == lbl) xl = v[j].w;
        }
        s += __expf(t - m);                       // tail (exp(-inf)=0 when absent)
        if (rem > 0 && ((nf4 << 2) + lane) == lbl && lane < rem) xl = t;

        #pragma unroll
        for (int o = 32; o > 0; o >>= 1) {
            s  += __shfl_xor(s, o);
            xl += __shfl_xor(xl, o);
        }

        float keep = (lbl >= 0 && lbl < 1024 && minmap[lbl]) ? 0.f : 1.f;
        float ce = __logf(s) + m - xl;
        acc_ce += (double)(ce * keep);
        acc_k  += (double)keep;
    }

    // Block reduction of the 4 wave accumulators.
    __shared__ double bce[WPB], bk[WPB];
    if (lane == 0) { bce[wave] = acc_ce; bk[wave] = acc_k; }
    __syncthreads();
    if (threadIdx.x == 0) {
        double a = 0.0, b = 0.0;
        #pragma unroll
        for (int w = 0; w < WPB; w++) { a += bce[w]; b += bk[w]; }
        part[blockIdx.x]           = a;
        part[nblocks + blockIdx.x] = b;
    }
}

// ---------------------------------------------------------------------------
// Finalize: single block reduces the per-block partials.
// ---------------------------------------------------------------------------
extern "C" __global__ __launch_bounds__(BLOCK) void crl_finalize(
    const double* __restrict__ part, int nblocks, float* __restrict__ out)
{
    double a = 0.0, b = 0.0;
    for (int i = threadIdx.x; i < nblocks; i += BLOCK) {
        a += part[i];
        b += part[nblocks + i];
    }
    #pragma unroll
    for (int o = 32; o > 0; o >>= 1) {
        a += __shfl_xor(a, o);
        b += __shfl_xor(b, o);
    }
    __shared__ double sa[WPB], sb[WPB];
    int wave = threadIdx.x >> 6, lane = threadIdx.x & 63;
    if (lane == 0) { sa[wave] = a; sb[wave] = b; }
    __syncthreads();
    if (threadIdx.x == 0) {
        double A = sa[0] + sa[1] + sa[2] + sa[3];
        double B = sb[0] + sb[1] + sb[2] + sb[3];
        out[0] = (float)(A / fmax(B, 1.0));   // LOSS_WEIGHT = 1.0
    }
}

extern "C" void kernel_launch(void* const* d_in, const int* in_sizes, int n_in,
                              void* d_out, int out_size, void* d_ws, size_t ws_size,
                              hipStream_t stream)
{
    const float* score = (const float*)d_in[0];
    const int*   label = (const int*)d_in[1];
    const int*   minc  = (const int*)d_in[2];
    const int N    = in_sizes[1];
    const int C    = in_sizes[0] / in_sizes[1];
    const int nmin = in_sizes[2];
    float*  out  = (float*)d_out;
    double* part = (double*)d_ws;    // needs 2*GRID*8 = 32 KiB of workspace

    hipLaunchKernelGGL(crl_main, dim3(GRID), dim3(BLOCK), 0, stream,
                       score, label, minc, N, C, nmin, part, GRID);
    hipLaunchKernelGGL(crl_finalize, dim3(1), dim3(BLOCK), 0, stream,
                       part, GRID, out);
}